// Round 13
// baseline (38.588 us; speedup 1.0000x reference)
//
#include <hip/hip_runtime.h>

#define H_    1024
#define B_    512
#define OUT_  512

typedef _Float16 half8 __attribute__((ext_vector_type(8)));
typedef _Float16 half4 __attribute__((ext_vector_type(4)));
typedef float    f32x4 __attribute__((ext_vector_type(4)));

__device__ __forceinline__ half8 cvt8(float4 lo, float4 hi) {
    half8 h;
    h[0] = (_Float16)lo.x; h[1] = (_Float16)lo.y; h[2] = (_Float16)lo.z; h[3] = (_Float16)lo.w;
    h[4] = (_Float16)hi.x; h[5] = (_Float16)hi.y; h[6] = (_Float16)hi.z; h[7] = (_Float16)hi.w;
    return h;
}

// Workgroup barrier WITHOUT the vmcnt(0) drain __syncthreads() emits.
__device__ __forceinline__ void barrier_nodrain() {
    asm volatile("s_waitcnt lgkmcnt(0)" ::: "memory");
    __builtin_amdgcn_s_barrier();
}

// ===========================================================================
// Dispatch 1, 768 blocks:
//  d <  512: kv-moment block. Tile 64 batches x 16 cols, FULL K (16 steps,
//            BK=64), dual B-operand (Wk,Wv) sharing one staged x-tile.
//            k,v stay in f32 accs; epilogue reduces them to power sums
//            mompart[bn][b][16]  (m_n = sum_j s^n, Mv_n = sum_j s^n(v+bv),
//            s = k/32). k,v never hit global memory.
//  d >= 512: q block (R12-proven 64x64, kz x2, 8 steps) -> qph f16 partials.
//  kv blocks with bn==0 also write out = bo (so out_kernel pure-atomicAdds).
// ===========================================================================
__global__ __launch_bounds__(256) void fused1_kernel(const float* __restrict__ x,
                                                     const float* __restrict__ Wq,
                                                     const float* __restrict__ Wk,
                                                     const float* __restrict__ Wv,
                                                     const float* __restrict__ bv,
                                                     const float* __restrict__ bo,
                                                     _Float16* __restrict__ qph,
                                                     float* __restrict__ mompart,
                                                     float* __restrict__ outp)
{
    __shared__ __align__(16) char smem[32768];

    const int tid  = threadIdx.x;
    const int lane = tid & 63;
    const int w    = tid >> 6;
    const int d    = blockIdx.x;

    if (d < 512) {
        // ================= kv-moment block =================
        _Float16* sA  = (_Float16*)smem;               // [2][64*64] = 16 KB
        _Float16* sBk = (_Float16*)(smem + 16384);     // [2][16*64] =  4 KB
        _Float16* sBv = (_Float16*)(smem + 24576);     // [2][16*64] =  4 KB

        const int fr = lane & 15, fg = lane >> 4;

        const int xcd = d & 7;
        const int j   = d >> 3;                // 0..63
        const int bm  = (j & 7) * 64;          // batch base
        const int bn  = xcd * 8 + (j >> 3);    // col-tile 0..63 (16 cols each)

        // bo-init (8 blocks: bn==0): out rows bm..bm+63 = bo
        if (bn == 0) {
            const int r   = tid >> 2;
            const int seg = tid & 3;
            float4* orow = (float4*)(outp + (size_t)(bm + r) * OUT_);
#pragma unroll
            for (int qq = 0; qq < 32; ++qq)
                orow[seg * 32 + qq] = ((const float4*)bo)[seg * 32 + qq];
        }

        // --- staging assignment ---
        const int srowA = tid >> 2;            // 0..63
        const int cqA   = tid & 3;
        const float* Ap = x + (size_t)(bm + srowA) * H_ + cqA * 16;
        const int g0 = srowA * 64 + (((2 * cqA)     ^ (srowA & 7)) << 3);
        const int g1 = srowA * 64 + (((2 * cqA + 1) ^ (srowA & 7)) << 3);

        const int half_  = tid >> 7;           // 0: Bk, 1: Bv
        const int srowB  = (tid & 127) >> 3;   // 0..15
        const int cqB    = tid & 7;
        const float* Wkv = half_ ? Wv : Wk;
        const float* Bp  = Wkv + (size_t)(bn * 16 + srowB) * H_ + cqB * 8;
        _Float16* sBmine = half_ ? sBv : sBk;
        const int gB = srowB * 64 + ((cqB ^ (srowB & 7)) << 3);

        f32x4 acck = {}, accv = {};

        float4 a0 = *(const float4*)(Ap + 0), a1 = *(const float4*)(Ap + 4);
        float4 a2 = *(const float4*)(Ap + 8), a3 = *(const float4*)(Ap + 12);
        float4 b0 = *(const float4*)(Bp + 0), b1 = *(const float4*)(Bp + 4);

        for (int t = 0; t < 16; ++t) {
            const int buf = (t & 1) << 12;     // A: 0/4096 halves
            const int bufB = (t & 1) << 10;    // B: 0/1024 halves
            half8 hA0 = cvt8(a0, a1), hA1 = cvt8(a2, a3);
            half8 hB  = cvt8(b0, b1);
            if (t < 15) {
                const float* An = Ap + (t + 1) * 64;
                const float* Bn = Bp + (t + 1) * 64;
                a0 = *(const float4*)(An + 0); a1 = *(const float4*)(An + 4);
                a2 = *(const float4*)(An + 8); a3 = *(const float4*)(An + 12);
                b0 = *(const float4*)(Bn + 0); b1 = *(const float4*)(Bn + 4);
            }
            *(half8*)&sA[buf + g0]    = hA0;
            *(half8*)&sA[buf + g1]    = hA1;
            *(half8*)&sBmine[bufB + gB] = hB;
            barrier_nodrain();

#pragma unroll
            for (int kh = 0; kh < 2; ++kh) {
                const int p = (((kh * 4 + fg) ^ (fr & 7)) << 3);
                half8 af = *(const half8*)&sA[buf + (w * 16 + fr) * 64 + p];
                half8 bk = *(const half8*)&sBk[bufB + fr * 64 + p];
                half8 bb = *(const half8*)&sBv[bufB + fr * 64 + p];
                acck = __builtin_amdgcn_mfma_f32_16x16x32_f16(af, bk, acck, 0, 0, 0);
                accv = __builtin_amdgcn_mfma_f32_16x16x32_f16(af, bb, accv, 0, 0, 0);
            }
        }

        // --- epilogue: dump k,v (f32) to LDS, reduce to moments ---
        __syncthreads();
        float* kd = (float*)smem;              // [64][20] padded
        float* vd = kd + 64 * 20;              // [64][20]
        {
            const int row0 = w * 16 + fg * 4;
            const int col  = fr;
#pragma unroll
            for (int rr = 0; rr < 4; ++rr) {
                kd[(row0 + rr) * 20 + col] = acck[rr];
                vd[(row0 + rr) * 20 + col] = accv[rr];
            }
        }
        __syncthreads();
        {
            const int b   = tid >> 2;          // 0..63
            const int sub = tid & 3;
            const int j0  = sub * 4;
            float m[8] = {}, Mv[8] = {};
#pragma unroll
            for (int jj = 0; jj < 4; ++jj) {
                float s  = kd[b * 20 + j0 + jj] * (1.0f / 32.0f);
                float vv = vd[b * 20 + j0 + jj] + bv[bn * 16 + j0 + jj];
                float p  = 1.0f;
#pragma unroll
                for (int n = 0; n < 8; ++n) {
                    m[n] += p;
                    Mv[n] = fmaf(p, vv, Mv[n]);
                    p *= s;
                }
            }
#pragma unroll
            for (int off = 1; off <= 2; off <<= 1)
#pragma unroll
                for (int n = 0; n < 8; ++n) {
                    m[n]  += __shfl_xor(m[n],  off, 64);
                    Mv[n] += __shfl_xor(Mv[n], off, 64);
                }
            if (sub == 0) {
                float* mout = mompart + ((size_t)bn * B_ + bm + b) * 16;
                f32x4 v0 = {m[0], m[1], m[2], m[3]};
                f32x4 v1 = {m[4], m[5], m[6], m[7]};
                f32x4 v2 = {Mv[0], Mv[1], Mv[2], Mv[3]};
                f32x4 v3 = {Mv[4], Mv[5], Mv[6], Mv[7]};
                ((f32x4*)mout)[0] = v0; ((f32x4*)mout)[1] = v1;
                ((f32x4*)mout)[2] = v2; ((f32x4*)mout)[3] = v3;
            }
        }
    } else {
        // ================= q block (R12-proven, q only) =================
        _Float16* sA = (_Float16*)smem;            // [2][64*64]
        _Float16* sB = (_Float16*)(smem + 16384);  // [2][64*64]

        const int wr = w >> 1, wc = w & 1;
        const int fr = lane & 15, fg = lane >> 4;

        const int id  = d - 512;               // 0..255
        const int xcd = id & 7;
        const int jj  = id >> 3;               // 0..31
        const int bm  = (jj & 7) * 64;
        const int t2  = jj >> 3;               // 0..3
        const int kz  = t2 & 1;
        const int bn  = (xcd * 2 + (t2 >> 1)) * 64;   // 0..960
        const int k0  = kz * 512;

        const int srow = tid >> 2;
        const int cq   = tid & 3;
        const float* Ap = x  + (size_t)(bm + srow) * H_ + k0 + cq * 16;
        const float* Bp = Wq + (size_t)(bn + srow) * H_ + k0 + cq * 16;

        const int g0    = (((2 * cq)     ^ (srow & 7)) << 3);
        const int g1    = (((2 * cq + 1) ^ (srow & 7)) << 3);
        const int wbase = srow * 64;

        f32x4 acc[2][2] = {};

        float4 a0 = *(const float4*)(Ap + 0), a1 = *(const float4*)(Ap + 4);
        float4 a2 = *(const float4*)(Ap + 8), a3 = *(const float4*)(Ap + 12);
        float4 b0 = *(const float4*)(Bp + 0), b1 = *(const float4*)(Bp + 4);
        float4 b2 = *(const float4*)(Bp + 8), b3 = *(const float4*)(Bp + 12);

        for (int t = 0; t < 8; ++t) {
            const int buf = (t & 1) << 12;
            half8 hA0 = cvt8(a0, a1), hA1 = cvt8(a2, a3);
            half8 hB0 = cvt8(b0, b1), hB1 = cvt8(b2, b3);
            if (t < 7) {
                const float* An = Ap + (t + 1) * 64;
                const float* Bn = Bp + (t + 1) * 64;
                a0 = *(const float4*)(An + 0); a1 = *(const float4*)(An + 4);
                a2 = *(const float4*)(An + 8); a3 = *(const float4*)(An + 12);
                b0 = *(const float4*)(Bn + 0); b1 = *(const float4*)(Bn + 4);
                b2 = *(const float4*)(Bn + 8); b3 = *(const float4*)(Bn + 12);
            }
            *(half8*)&sA[buf + wbase + g0] = hA0;
            *(half8*)&sA[buf + wbase + g1] = hA1;
            *(half8*)&sB[buf + wbase + g0] = hB0;
            *(half8*)&sB[buf + wbase + g1] = hB1;
            barrier_nodrain();

#pragma unroll
            for (int kh = 0; kh < 2; ++kh) {
                const int p = (((kh * 4 + fg) ^ (fr & 7)) << 3);
                half8 af[2], bf[2];
#pragma unroll
                for (int mi = 0; mi < 2; ++mi)
                    af[mi] = *(const half8*)&sA[buf + (wr * 32 + mi * 16 + fr) * 64 + p];
#pragma unroll
                for (int ni = 0; ni < 2; ++ni)
                    bf[ni] = *(const half8*)&sB[buf + (wc * 32 + ni * 16 + fr) * 64 + p];
#pragma unroll
                for (int mi = 0; mi < 2; ++mi)
#pragma unroll
                    for (int ni = 0; ni < 2; ++ni)
                        acc[mi][ni] = __builtin_amdgcn_mfma_f32_16x16x32_f16(
                                          af[mi], bf[ni], acc[mi][ni], 0, 0, 0);
            }
        }

        _Float16* Cb = qph + (size_t)kz * B_ * H_ + (size_t)bm * H_ + bn;
#pragma unroll
        for (int mi = 0; mi < 2; ++mi) {
            const int r0 = wr * 32 + mi * 16 + fg * 4;
#pragma unroll
            for (int ni = 0; ni < 2; ++ni) {
                const int col = wc * 32 + ni * 16 + fr;
#pragma unroll
                for (int r = 0; r < 4; ++r)
                    Cb[(size_t)(r0 + r) * H_ + col] = (_Float16)acc[mi][ni][r];
            }
        }
    }
}

// ===========================================================================
// Dispatch 2: eval. Per batch: sum 64 moment-partials, apply 1/n!, Horner
// on c = q (2 f16 kz-partials summed) -> attnh f16.
// ===========================================================================
__global__ __launch_bounds__(256) void eval_kernel(const _Float16* __restrict__ qph,
                                                   const float* __restrict__ mompart,
                                                   _Float16* __restrict__ attnh)
{
    __shared__ float red2[16][17];
    __shared__ float sm[16];
    const int b   = blockIdx.x;
    const int tid = threadIdx.x;

    {   // reduce 64 partials: thread (n = tid>>4, p2 = tid&15) sums 4 parts
        const int n  = tid >> 4;
        const int p2 = tid & 15;
        float s = 0.0f;
#pragma unroll
        for (int q = 0; q < 4; ++q)
            s += mompart[((size_t)(p2 + q * 16) * B_ + b) * 16 + n];
        red2[n][p2] = s;
    }
    __syncthreads();
    if (tid < 16) {
        const float invfact[8] = {1.f, 1.f, 0.5f, 1.f/6.f, 1.f/24.f,
                                  1.f/120.f, 1.f/720.f, 1.f/5040.f};
        float s = 0.0f;
#pragma unroll
        for (int p2 = 0; p2 < 16; ++p2) s += red2[tid][p2];
        sm[tid] = s * invfact[tid & 7];
    }
    __syncthreads();

    half4 qa = ((const half4*)(qph + (size_t)b * H_))[tid];
    half4 qb = ((const half4*)(qph + (size_t)(B_ + b) * H_))[tid];
    half4 o;
#pragma unroll
    for (int e = 0; e < 4; ++e) {
        float c = (float)qa[e] + (float)qb[e];
        float den = sm[7];
#pragma unroll
        for (int n = 6; n >= 0; --n) den = fmaf(den, c, sm[n]);
        float num = sm[15];
#pragma unroll
        for (int n = 14; n >= 8; --n) num = fmaf(num, c, sm[n]);
        o[e] = (_Float16)(num / den);
    }
    ((half4*)attnh)[b * 256 + tid] = o;
}

// ===========================================================================
// Dispatch 3 (R12-proven): out += attn @ Wo^T, bias pre-initialized.
// BM=BN=32, K-split x2 -> 512 blocks, 8 steps, f32 atomicAdd (2 adds/elem).
// ===========================================================================
__global__ __launch_bounds__(256) void out_kernel(const _Float16* __restrict__ attnh,
                                                  const float* __restrict__ Wo,
                                                  float* __restrict__ outp)
{
    __shared__ __align__(16) _Float16 sA[2][32 * 64];
    __shared__ __align__(16) _Float16 sB[2][32 * 64];

    const int tid  = threadIdx.x;
    const int lane = tid & 63;
    const int w    = tid >> 6;
    const int wr   = w >> 1, wc = w & 1;
    const int fr   = lane & 15, fg = lane >> 4;

    const int d   = blockIdx.x;
    const int xcd = d & 7;
    const int j   = d >> 3;                  // 0..63
    const int kz  = xcd & 1;
    const int bm  = (j & 15) * 32;
    const int bn  = ((xcd >> 1) * 4 + (j >> 4)) * 32;   // 0..480
    const int k0  = kz * 512;

    const int srow = tid >> 3;
    const int cg_  = tid & 7;
    const _Float16* Ap = attnh + (size_t)(bm + srow) * H_ + k0 + cg_ * 8;
    const float*    Bp = Wo    + (size_t)(bn + srow) * H_ + k0 + cg_ * 8;

    const int sw    = (cg_ ^ (srow & 7)) << 3;
    const int wbase = srow * 64;

    f32x4 acc = {};

    half8  a0 = *(const half8*)Ap;
    float4 b0 = *(const float4*)(Bp + 0), b1 = *(const float4*)(Bp + 4);

    for (int t = 0; t < 8; ++t) {
        const int buf = t & 1;
        half8 hA = a0;
        half8 hB = cvt8(b0, b1);
        if (t < 7) {
            a0 = *(const half8*)(Ap + (t + 1) * 64);
            b0 = *(const float4*)(Bp + (t + 1) * 64);
            b1 = *(const float4*)(Bp + (t + 1) * 64 + 4);
        }
        *(half8*)&sA[buf][wbase + sw] = hA;
        *(half8*)&sB[buf][wbase + sw] = hB;
        barrier_nodrain();

#pragma unroll
        for (int kh = 0; kh < 2; ++kh) {
            const int p = (((kh * 4 + fg) ^ (fr & 7)) << 3);
            half8 af = *(const half8*)&sA[buf][(wr * 16 + fr) * 64 + p];
            half8 bf = *(const half8*)&sB[buf][(wc * 16 + fr) * 64 + p];
            acc = __builtin_amdgcn_mfma_f32_16x16x32_f16(af, bf, acc, 0, 0, 0);
        }
    }

    const int row0 = bm + wr * 16 + fg * 4;
    const int col  = bn + wc * 16 + fr;
#pragma unroll
    for (int r = 0; r < 4; ++r)
        atomicAdd(&outp[(size_t)(row0 + r) * OUT_ + col], acc[r]);
}

extern "C" void kernel_launch(void* const* d_in, const int* in_sizes, int n_in,
                              void* d_out, int out_size, void* d_ws, size_t ws_size,
                              hipStream_t stream)
{
    const float* x  = (const float*)d_in[0];
    const float* Wq = (const float*)d_in[1];
    const float* Wk = (const float*)d_in[2];
    const float* Wv = (const float*)d_in[3];
    const float* bv = (const float*)d_in[4];
    const float* Wo = (const float*)d_in[5];
    const float* bo = (const float*)d_in[6];
    float* out = (float*)d_out;

    char* ws = (char*)d_ws;
    _Float16* qph     = (_Float16*)ws;                // [2][512][1024] f16 = 2 MB
    _Float16* attnh   = (_Float16*)(ws + (2 << 20));  // [512][1024] f16 = 1 MB
    float*    mompart = (float*)   (ws + (4 << 20));  // [64][512][16] f32 = 2 MB

    fused1_kernel<<<dim3(768), 256, 0, stream>>>(x, Wq, Wk, Wv, bv, bo,
                                                 qph, mompart, out);
    eval_kernel<<<dim3(B_), 256, 0, stream>>>(qph, mompart, attnh);
    out_kernel<<<dim3(512), 256, 0, stream>>>(attnh, Wo, out);
}